// Round 1
// 892.879 us; speedup vs baseline: 1.3892x; 1.3892x over previous
//
#include <hip/hip_runtime.h>
#include <math.h>

#define NPFS   4
#define NFM    512
#define NP     256
#define BATCH  128
#define NBLK   (BATCH * NPFS)   // 512 pfaffians
#define THREADS 1024
#define NWAVES (THREADS / 64)
#define TRI    ((NP * (NP - 1)) / 2)   // 32640 strict-lower elements

// fp32 packed strict-lower triangle, each row padded to a multiple of 4
// floats so every row starts 16B-aligned (ds_read_b128 float4 in the sweep).
// rowoff(256) = 33024 floats.
__device__ __forceinline__ int rowoff(int r) {
    int q = r >> 2, rem = r & 3;
    int g = 2 * q * q + q;
    if (rem > 0) g += q;
    if (rem > 1) g += q + 1;
    if (rem > 2) g += q + 1;
    return g << 2;
}
#define LFLOATS 33024

extern "C" __global__ __launch_bounds__(THREADS, 4)
void MultiPf_32469952758284_kernel(const float* __restrict__ F,
                                   const int* __restrict__ idx,
                                   float* __restrict__ ws)
{
    extern __shared__ char smemc[];
    float* L      = (float*)smemc;              // 33024 floats (132096 B)
    float* t1     = (float*)(smemc + 132096);   // 256 (16B-aligned)
    float* v1     = (float*)(smemc + 133120);   // 256
    float* colbuf = (float*)(smemc + 134144);   // 256 (current pivot column)
    int*   idxL   = (int*)(smemc + 135168);     // 256
    // total 136192 B (one block/CU; 16 waves for latency hiding)

    const int tid = threadIdx.x;
    const int bid = blockIdx.x;
    const int b = bid >> 2;   // batch
    const int s = bid & 3;    // pf-state
    const float* __restrict__ Fs = F + (size_t)s * NFM * NFM;

    if (tid < NP) {
        idxL[tid] = idx[b * NP + tid];
        t1[tid] = 0.0f;      // columns < k+2 must read tau=v=0 in the sweep
        v1[tid] = 0.0f;
    }
    __syncthreads();

    // ---- gather strict lower triangle: A[r][c] = 0.5*(F[ir][ic] - F[ic][ir])
    // Also seed colbuf with column 0 for the first pivot search.
    for (int e = tid; e < TRI; e += THREADS) {
        int r = (int)((1.0f + sqrtf(1.0f + 8.0f * (float)e)) * 0.5f);
        while (r * (r - 1) / 2 > e) --r;
        while (r * (r + 1) / 2 <= e) ++r;
        int c = e - r * (r - 1) / 2;
        int ir = idxL[r], ic = idxL[c];
        float val = 0.5f * (Fs[(size_t)ir * NFM + ic] - Fs[(size_t)ic * NFM + ir]);
        L[rowoff(r) + c] = val;
        if (c == 0) colbuf[r] = val;
    }

    float sgn = 1.0f, la = 0.0f;   // maintained redundantly on tid<256; tid 0 writes
    __syncthreads();

    for (int k = 0; k < NP; k += 2) {
        const int p = k + 1;

        // ---- Phase A (waves 0-3 only): wave-local redundant argmax + fused
        //      symmetric swap + tau/v extraction. No cross-wave comms -> no
        //      extra barrier. Waves 4-15 fall through to B1.
        if (tid < NP) {
            const int lane = tid & 63;
            // argmax_{r>k} |colbuf[r]|, tie -> lowest r (matches jnp.argmax).
            // key = (|x| bits << 32) | (255 - idx): ULL max == (abs desc, idx asc).
            const float4 c4 = *(const float4*)(colbuf + (lane << 2));
            unsigned long long key = 0ull;
            {
                const int base = lane << 2;
                const float xs[4] = {c4.x, c4.y, c4.z, c4.w};
                #pragma unroll
                for (int jj = 0; jj < 4; ++jj) {
                    const int i2 = base + jj;
                    const unsigned int ab = __float_as_uint(xs[jj]) & 0x7fffffffu;
                    const unsigned long long kk =
                        ((unsigned long long)ab << 32) | (unsigned)(NP - 1 - i2);
                    if (i2 > k && kk > key) key = kk;
                }
            }
            #pragma unroll
            for (int o = 1; o < 64; o <<= 1) {
                const unsigned long long ok = __shfl_xor(key, o);
                if (ok > key) key = ok;
            }
            const int kp = (NP - 1) - (int)(key & 0xffu);
            const float cs = colbuf[kp];     // broadcast re-read of signed value
            const float piv = -cs;           // piv = A_post[k][k+1] = -L_pre[kp][k]
            const float rpiv = 1.0f / piv;
            if (kp != p) sgn = -sgn;
            if (piv < 0.0f) sgn = -sgn;
            la += logf(fabsf(piv));

            // P2: fused symmetric swap (p<->kp) + tau/v extraction.
            // Race-free: thread r owns exactly the L elements it reads/writes.
            const int r = tid;
            if (r >= k + 2) {
                const int orr = rowoff(r);
                if (kp == p) {
                    t1[r] = L[orr + k] * rpiv;
                    v1[r] = L[orr + p];
                } else if (r < kp) {
                    const int okp = rowoff(kp);
                    float a0 = L[orr + p], a1 = L[okp + r];
                    L[orr + p] = -a1; L[okp + r] = -a0;
                    v1[r] = -a1;
                    t1[r] = L[orr + k] * rpiv;
                } else if (r == kp) {
                    const int op_ = rowoff(p);
                    float t = L[op_ + k];                  // = L_pre[p][k]
                    t1[r] = t * rpiv;
                    L[op_ + k] = L[orr + k]; L[orr + k] = t;  // col-k swap
                    float wv = -L[orr + p];                // (kp,p) negates
                    L[orr + p] = wv; v1[r] = wv;
                } else { // r > kp
                    float t = L[orr + p], u2 = L[orr + kp];
                    L[orr + p] = u2; L[orr + kp] = t;
                    v1[r] = u2;
                    t1[r] = L[orr + k] * rpiv;
                }
            }
            if (r == k || r == p) { t1[r] = 0.0f; v1[r] = 0.0f; }
        }
        __syncthreads();   // B1: swaps + t1/v1 visible

        // ---- Phase B: rank-2 trailing sweep, one row-PAIR per wave-iteration.
        // Pair (a=k+2+j, bb=255-j): combined padded length ~64 float4 chunks,
        // lanes cover two CONTIGUOUS chunk runs -> conflict-free ds_read_b128.
        // t1/v1 chunk reads: 2-way same-address (free); row scalars: broadcast.
        // Captures column k+2 into colbuf for the next argmax.
        {
            const int w    = tid >> 6;
            const int lane = tid & 63;
            const int nc   = k + 2;
            const int cb   = nc & ~3;
            const int comp = nc & 3;            // 0 or 2
            const int npairs = (NP - nc) >> 1;
            for (int j = w; j < npairs; j += NWAVES) {
                const int a  = nc + j;
                const int bb = NP - 1 - j;
                const int oa = rowoff(a);
                const int ob = rowoff(bb);
                const int na = (((a + 3) & ~3) - cb) >> 2;
                const int nT = na + ((((bb + 3) & ~3) - cb) >> 2);
                const float ta = t1[a],  va = v1[a];
                const float tb = t1[bb], vb = v1[bb];
                for (int t = lane; t < nT; t += 64) {   // nT <= 65: 1-2 iters
                    const bool inA = t < na;
                    const int  ch  = inA ? t : (t - na);
                    const int  c   = cb + (ch << 2);
                    const int  off = (inA ? oa : ob) + c;
                    const float tr = inA ? ta : tb;
                    const float vr = inA ? va : vb;
                    float4 l = *(float4*)(L + off);
                    const float4 tt = *(const float4*)(t1 + c);
                    const float4 vv = *(const float4*)(v1 + c);
                    l.x += vr * tt.x - tr * vv.x;
                    l.y += vr * tt.y - tr * vv.y;
                    l.z += vr * tt.z - tr * vv.z;
                    l.w += vr * tt.w - tr * vv.w;
                    *(float4*)(L + off) = l;
                    // chunk 0 of each row segment contains column nc
                    if (ch == 0) colbuf[inA ? a : bb] = comp ? l.z : l.x;
                }
            }
        }
        __syncthreads();   // B2: sweep + colbuf ready for next step
    }

    if (tid == 0) {
        ws[bid * 2 + 0] = sgn;
        ws[bid * 2 + 1] = la;
    }
}

extern "C" __global__ void MultiPf_combine_kernel(const float* __restrict__ ws,
                                                  float* __restrict__ out)
{
    int b = threadIdx.x + blockIdx.x * blockDim.x;
    if (b >= BATCH) return;
    float sg[NPFS], lg[NPFS];
    float m = -INFINITY;
    for (int j = 0; j < NPFS; ++j) {
        sg[j] = ws[(b * NPFS + j) * 2 + 0];
        lg[j] = ws[(b * NPFS + j) * 2 + 1];
        m = fmaxf(m, lg[j]);
    }
    float val = 0.0f;
    for (int j = 0; j < NPFS; ++j)
        val += sg[j] * expf(lg[j] - m);
    float osgn = (val > 0.0f) ? 1.0f : ((val < 0.0f) ? -1.0f : 0.0f);
    out[b]         = osgn;
    out[BATCH + b] = m + logf(fabsf(val));
}

extern "C" void kernel_launch(void* const* d_in, const int* in_sizes, int n_in,
                              void* d_out, int out_size, void* d_ws, size_t ws_size,
                              hipStream_t stream)
{
    (void)in_sizes; (void)n_in; (void)out_size; (void)ws_size;
    const float* F   = (const float*)d_in[0];
    const int*   idx = (const int*)d_in[1];
    float* out = (float*)d_out;
    float* ws  = (float*)d_ws;

    const size_t smem_bytes = 136192;   // see LDS layout in kernel

    // Raise dynamic-LDS cap above the 64 KB default (gfx950: 160 KB/CU).
    (void)hipFuncSetAttribute((const void*)MultiPf_32469952758284_kernel,
                              hipFuncAttributeMaxDynamicSharedMemorySize,
                              (int)smem_bytes);

    MultiPf_32469952758284_kernel<<<NBLK, THREADS, smem_bytes, stream>>>(F, idx, ws);
    MultiPf_combine_kernel<<<1, 128, 0, stream>>>(ws, out);
}

// Round 2
// 600.941 us; speedup vs baseline: 2.0641x; 1.4858x over previous
//
#include <hip/hip_runtime.h>
#include <math.h>

#define NPFS   4
#define NFM    512
#define NP     256
#define BATCH  128
#define NBLK   (BATCH * NPFS)   // 512 pfaffians
#define THREADS 1024
#define NWAVES (THREADS / 64)
#define TRI    ((NP * (NP - 1)) / 2)   // 32640 strict-lower elements
#define NB     4                 // steps per panel block -> rank-8 trailing update
#define BSTEPS (2 * NB)          // 8 columns consumed per block

// fp32 packed strict-lower triangle, each row padded to a multiple of 4
// floats so every row starts 16B-aligned. rowoff(256) = 33024 floats.
__device__ __forceinline__ int rowoff(int r) {
    int q = r >> 2, rem = r & 3;
    int g = 2 * q * q + q;
    if (rem > 0) g += q;
    if (rem > 1) g += q + 1;
    if (rem > 2) g += q + 1;
    return g << 2;
}

extern "C" __global__ __launch_bounds__(THREADS, 4)
void MultiPf_32469952758284_kernel(const float* __restrict__ F,
                                   const int* __restrict__ idx,
                                   float* __restrict__ ws)
{
    extern __shared__ char smemc[];
    float* L      = (float*)smemc;                  // 33024 f (132096 B)
    float* Tcol   = (float*)(smemc + 132096);       // NB*256 f (tau_j, col-major)
    float* Vcol   = (float*)(smemc + 136192);       // NB*256 f (v_j, col-major)
    float* TVrow  = (float*)(smemc + 140288);       // 256*8 f  (row-major dup: t0..3,v0..3)
    float* colbuf = (float*)(smemc + 148480);       // 256 f (current pivot column)
    int*   idxL   = (int*)(smemc + 149504);         // 256
    // total 150528 B (one block/CU; 16 waves)

    const int tid = threadIdx.x;
    const int bid = blockIdx.x;
    const int b = bid >> 2;   // batch
    const int s = bid & 3;    // pf-state
    const float* __restrict__ Fs = F + (size_t)s * NFM * NFM;

    if (tid < NP) idxL[tid] = idx[b * NP + tid];
    __syncthreads();

    // ---- gather strict lower triangle: A[r][c] = 0.5*(F[ir][ic] - F[ic][ir])
    // Also seed colbuf with column 0 for the first pivot search.
    for (int e = tid; e < TRI; e += THREADS) {
        int r = (int)((1.0f + sqrtf(1.0f + 8.0f * (float)e)) * 0.5f);
        while (r * (r - 1) / 2 > e) --r;
        while (r * (r + 1) / 2 <= e) ++r;
        int c = e - r * (r - 1) / 2;
        int ir = idxL[r], ic = idxL[c];
        float val = 0.5f * (Fs[(size_t)ir * NFM + ic] - Fs[(size_t)ic * NFM + ir]);
        L[rowoff(r) + c] = val;
        if (c == 0) colbuf[r] = val;
    }

    float sgn = 1.0f, la = 0.0f;   // redundant on tid<256; tid 0 writes out
    __syncthreads();

    for (int kb = 0; kb < NP / BSTEPS; ++kb) {
        const int k0 = kb * BSTEPS;

        // ================= panel: NB steps, lazy trailing =================
        for (int j = 0; j < NB; ++j) {
            const int k = k0 + 2 * j;
            const int p = k + 1;

            // ---- A1: refresh column k with pending in-block terms jj<j,
            //      write back + colbuf. (j==0: trailing already left colbuf fresh.)
            if (j > 0) {
                if (tid > k && tid < NP) {
                    const int r = tid;
                    const int orr = rowoff(r);
                    float x = L[orr + k];
                    for (int jj = 0; jj < j; ++jj) {
                        const float tk  = Tcol[jj * NP + k];
                        const float vk  = Vcol[jj * NP + k];
                        const float tr_ = Tcol[jj * NP + r];
                        const float vr_ = Vcol[jj * NP + r];
                        x += vr_ * tk - tr_ * vk;
                    }
                    L[orr + k] = x;
                    colbuf[r] = x;
                }
                __syncthreads();   // B1
            }

            // ---- argmax + P2 swap + panel-row physical swap
            int kp = 0; float rpiv = 0.0f;
            if (tid < NP) {
                const int lane = tid & 63;
                // argmax_{r>k} |colbuf[r]|, tie -> lowest r (matches jnp.argmax)
                const float4 c4 = *(const float4*)(colbuf + (lane << 2));
                unsigned long long key = 0ull;
                {
                    const int base = lane << 2;
                    const float xs[4] = {c4.x, c4.y, c4.z, c4.w};
                    #pragma unroll
                    for (int ii = 0; ii < 4; ++ii) {
                        const int i2 = base + ii;
                        const unsigned int ab = __float_as_uint(xs[ii]) & 0x7fffffffu;
                        const unsigned long long kk =
                            ((unsigned long long)ab << 32) | (unsigned)(NP - 1 - i2);
                        if (i2 > k && kk > key) key = kk;
                    }
                }
                #pragma unroll
                for (int o = 1; o < 64; o <<= 1) {
                    const unsigned long long ok = __shfl_xor(key, o);
                    if (ok > key) key = ok;
                }
                kp = (NP - 1) - (int)(key & 0xffu);
                const float cs = colbuf[kp];     // broadcast
                const float piv = -cs;           // piv = A_post[k][k+1] = -L_pre[kp][k]
                rpiv = 1.0f / piv;
                if (kp != p) sgn = -sgn;
                if (piv < 0.0f) sgn = -sgn;
                la += logf(fabsf(piv));

                const int r = tid;
                if (kp != p) {
                    // symmetric swap p<->kp on L (only live region; thread r owns
                    // exactly the elements it touches)
                    if (r >= k + 2) {
                        const int orr = rowoff(r);
                        if (r < kp) {
                            const int okp = rowoff(kp);
                            float a0 = L[orr + p], a1 = L[okp + r];
                            L[orr + p] = -a1; L[okp + r] = -a0;
                        } else if (r == kp) {
                            const int op_ = rowoff(p);
                            float t = L[op_ + k];
                            L[op_ + k] = L[orr + k]; L[orr + k] = t;  // col-k swap
                            L[orr + p] = -L[orr + p];                 // (kp,p) negates
                        } else { // r > kp
                            float t = L[orr + p];
                            L[orr + p] = L[orr + kp]; L[orr + kp] = t;
                        }
                    }
                    // physical swap of rows p,kp in accumulated panels (jj<j),
                    // done by otherwise-idle threads jj (< j <= 3 < k+2).
                    if (tid < j) {
                        const int jj = tid;
                        float a, b2;
                        a = Tcol[jj * NP + p]; b2 = Tcol[jj * NP + kp];
                        Tcol[jj * NP + p] = b2; Tcol[jj * NP + kp] = a;
                        a = Vcol[jj * NP + p]; b2 = Vcol[jj * NP + kp];
                        Vcol[jj * NP + p] = b2; Vcol[jj * NP + kp] = a;
                        a = TVrow[p * 8 + jj]; b2 = TVrow[kp * 8 + jj];
                        TVrow[p * 8 + jj] = b2; TVrow[kp * 8 + jj] = a;
                        a = TVrow[p * 8 + 4 + jj]; b2 = TVrow[kp * 8 + 4 + jj];
                        TVrow[p * 8 + 4 + jj] = b2; TVrow[kp * 8 + 4 + jj] = a;
                    }
                }
            }
            __syncthreads();   // B2

            // ---- A2: refresh column p (post-swap) + extract tau/v into panels
            if (tid < NP) {
                const int r = tid;
                float tau = 0.0f, vv = 0.0f;
                if (r >= k + 2) {
                    const int orr = rowoff(r);
                    tau = L[orr + k] * rpiv;
                    float y = L[orr + p];
                    for (int jj = 0; jj < j; ++jj) {
                        const float tp_ = Tcol[jj * NP + p];   // post-swap rows
                        const float vp_ = Vcol[jj * NP + p];
                        const float tr_ = Tcol[jj * NP + r];
                        const float vr_ = Vcol[jj * NP + r];
                        y += vr_ * tp_ - tr_ * vp_;
                    }
                    vv = y;
                }
                Tcol[j * NP + r] = tau;
                Vcol[j * NP + r] = vv;
                TVrow[r * 8 + j] = tau;
                TVrow[r * 8 + 4 + j] = vv;
            }
            __syncthreads();   // B3
        }

        // ================= trailing rank-2*NB update =================
        // Lane owns 4 FIXED columns -> tau/v column values preloaded into
        // registers once per block. Per row: 1 b128 read + 1 b128 write of L
        // + 2 uniform b128 broadcasts (TVrow). Captures column kend -> colbuf.
        const int kend = k0 + BSTEPS;   // multiple of 8 -> 16B aligned
        if (kend < NP) {
            const int w = tid >> 6;
            const int lane = tid & 63;
            const int c0 = kend + (lane << 2);
            float4 tj0 = {0,0,0,0}, tj1 = {0,0,0,0}, tj2 = {0,0,0,0}, tj3 = {0,0,0,0};
            float4 vj0 = {0,0,0,0}, vj1 = {0,0,0,0}, vj2 = {0,0,0,0}, vj3 = {0,0,0,0};
            if (c0 < NP) {
                tj0 = *(const float4*)(Tcol + 0 * NP + c0);
                tj1 = *(const float4*)(Tcol + 1 * NP + c0);
                tj2 = *(const float4*)(Tcol + 2 * NP + c0);
                tj3 = *(const float4*)(Tcol + 3 * NP + c0);
                vj0 = *(const float4*)(Vcol + 0 * NP + c0);
                vj1 = *(const float4*)(Vcol + 1 * NP + c0);
                vj2 = *(const float4*)(Vcol + 2 * NP + c0);
                vj3 = *(const float4*)(Vcol + 3 * NP + c0);
            }
            for (int r = kend + 1 + w; r < NP; r += NWAVES) {
                const float4 t4 = *(const float4*)(TVrow + r * 8);      // tau_j[r]
                const float4 v4 = *(const float4*)(TVrow + r * 8 + 4);  // v_j[r]
                if (c0 < r) {
                    float* Lp = L + rowoff(r) + c0;
                    float4 l = *(float4*)Lp;
                    // jj ascending: same per-element rounding chain as reference
                    l.x += v4.x * tj0.x - t4.x * vj0.x;
                    l.y += v4.x * tj0.y - t4.x * vj0.y;
                    l.z += v4.x * tj0.z - t4.x * vj0.z;
                    l.w += v4.x * tj0.w - t4.x * vj0.w;
                    l.x += v4.y * tj1.x - t4.y * vj1.x;
                    l.y += v4.y * tj1.y - t4.y * vj1.y;
                    l.z += v4.y * tj1.z - t4.y * vj1.z;
                    l.w += v4.y * tj1.w - t4.y * vj1.w;
                    l.x += v4.z * tj2.x - t4.z * vj2.x;
                    l.y += v4.z * tj2.y - t4.z * vj2.y;
                    l.z += v4.z * tj2.z - t4.z * vj2.z;
                    l.w += v4.z * tj2.w - t4.z * vj2.w;
                    l.x += v4.w * tj3.x - t4.w * vj3.x;
                    l.y += v4.w * tj3.y - t4.w * vj3.y;
                    l.z += v4.w * tj3.z - t4.w * vj3.z;
                    l.w += v4.w * tj3.w - t4.w * vj3.w;
                    *(float4*)Lp = l;
                    if (lane == 0) colbuf[r] = l.x;   // column kend for next argmax
                }
            }
        }
        __syncthreads();
    }

    if (tid == 0) {
        ws[bid * 2 + 0] = sgn;
        ws[bid * 2 + 1] = la;
    }
}

extern "C" __global__ void MultiPf_combine_kernel(const float* __restrict__ ws,
                                                  float* __restrict__ out)
{
    int b = threadIdx.x + blockIdx.x * blockDim.x;
    if (b >= BATCH) return;
    float sg[NPFS], lg[NPFS];
    float m = -INFINITY;
    for (int j = 0; j < NPFS; ++j) {
        sg[j] = ws[(b * NPFS + j) * 2 + 0];
        lg[j] = ws[(b * NPFS + j) * 2 + 1];
        m = fmaxf(m, lg[j]);
    }
    float val = 0.0f;
    for (int j = 0; j < NPFS; ++j)
        val += sg[j] * expf(lg[j] - m);
    float osgn = (val > 0.0f) ? 1.0f : ((val < 0.0f) ? -1.0f : 0.0f);
    out[b]         = osgn;
    out[BATCH + b] = m + logf(fabsf(val));
}

extern "C" void kernel_launch(void* const* d_in, const int* in_sizes, int n_in,
                              void* d_out, int out_size, void* d_ws, size_t ws_size,
                              hipStream_t stream)
{
    (void)in_sizes; (void)n_in; (void)out_size; (void)ws_size;
    const float* F   = (const float*)d_in[0];
    const int*   idx = (const int*)d_in[1];
    float* out = (float*)d_out;
    float* ws  = (float*)d_ws;

    const size_t smem_bytes = 150528;   // see LDS layout in kernel

    // Raise dynamic-LDS cap above the 64 KB default (gfx950: 160 KB/CU).
    (void)hipFuncSetAttribute((const void*)MultiPf_32469952758284_kernel,
                              hipFuncAttributeMaxDynamicSharedMemorySize,
                              (int)smem_bytes);

    MultiPf_32469952758284_kernel<<<NBLK, THREADS, smem_bytes, stream>>>(F, idx, ws);
    MultiPf_combine_kernel<<<1, 128, 0, stream>>>(ws, out);
}